// Round 6
// baseline (178.438 us; speedup 1.0000x reference)
//
#include <hip/hip_runtime.h>
#include <hip/hip_bf16.h>

// Problem constants (reference: T=2048, B=2, D_MODEL=1024, H=16, HEAD_DIM=64)
#define TT 2048
#define BB 2
#define CC 1024
#define HH 16
#define DD 64
#define MM (TT * BB)   // 4096 rows in the projection GEMMs

typedef short bf16x8 __attribute__((ext_vector_type(8)));   // 8 bf16 in 4 VGPRs
typedef float f32x4  __attribute__((ext_vector_type(4)));

// float -> bf16 (round-nearest-even), bit-level
__device__ inline ushort f2b(float f) {
    union { float f; unsigned u; } v; v.f = f;
    unsigned r = v.u + 0x7FFFu + ((v.u >> 16) & 1u);
    return (ushort)(r >> 16);
}

// pack 2 floats -> 2 bf16 in one dword
__device__ inline unsigned pack_bf16(float a, float b) {
    __hip_bfloat162 h = __float22bfloat162_rn(make_float2(a, b));
    union { __hip_bfloat162 h; unsigned u; } c; c.h = h;
    return c.u;
}

// async global->LDS, 16B per lane (GEMM staging only)
__device__ inline void gload_lds16(const ushort* g, ushort* l) {
    __builtin_amdgcn_global_load_lds(
        (const __attribute__((address_space(1))) void*)g,
        (__attribute__((address_space(3))) void*)l, 16, 0, 0);
}

// ---------------------------------------------------------------------------
// fp32 -> bf16 convert, x and all four W in one launch.
// ---------------------------------------------------------------------------
#define XQUADS (MM * CC / 4)          // 1048576
#define WQUADS (CC * CC / 4)          // 262144
__global__ __launch_bounds__(256) void conv_all(const float* __restrict__ x,
                                                const float* __restrict__ Wq,
                                                const float* __restrict__ Wk,
                                                const float* __restrict__ Wv,
                                                const float* __restrict__ Wo,
                                                ushort* __restrict__ dst) {
    int idx = blockIdx.x * 256 + threadIdx.x;    // quad index
    const float* src;
    int off;
    if (idx < XQUADS) {
        src = x; off = idx;
    } else {
        int wi = (idx - XQUADS) >> 18;           // WQUADS == 2^18
        off = (idx - XQUADS) & (WQUADS - 1);
        src = (wi == 0) ? Wq : (wi == 1) ? Wk : (wi == 2) ? Wv : Wo;
    }
    float4 v = ((const float4*)src)[off];
    ushort4 o = {f2b(v.x), f2b(v.y), f2b(v.z), f2b(v.w)};
    ((ushort4*)dst)[idx] = o;
}

// ---------------------------------------------------------------------------
// bf16 MFMA NT GEMM (m97 structure), 128x128 tile, BK=32, 4 waves (2x2).
// Fused QKV (grid.y = 24): wsel = by>>3 picks B/out; epilogue scatters bf16
// to (B,H,T,D); Q scaled by 1/sqrt(64)*log2(e) so attention uses exp2 raw.
// ---------------------------------------------------------------------------
__global__ __launch_bounds__(256) void gemm_qkv(const ushort* __restrict__ A,
                                                const ushort* __restrict__ B0,
                                                const ushort* __restrict__ B1,
                                                const ushort* __restrict__ B2,
                                                ushort* __restrict__ Oq,
                                                ushort* __restrict__ Ok,
                                                ushort* __restrict__ Ov) {
    __shared__ __align__(16) ushort As[128 * 32];
    __shared__ __align__(16) ushort Bs[128 * 32];

    const int tid = threadIdx.x;
    const int wave = tid >> 6, lane = tid & 63;
    const int quad = lane >> 4, l16 = lane & 15;
    const int wm = wave >> 1, wn = wave & 1;

    const int bm = blockIdx.x * 128;
    const int by = blockIdx.y;
    const int wsel = by >> 3;
    const ushort* Bp = (wsel == 0) ? B0 : (wsel == 1) ? B1 : B2;
    const int bn = (by & 7) * 128;

    const int srow = lane >> 2;
    const int scol = (lane & 3) * 8;

    f32x4 acc[4][4];
#pragma unroll
    for (int i = 0; i < 4; i++)
#pragma unroll
        for (int j = 0; j < 4; j++) acc[i][j] = (f32x4){0.f, 0.f, 0.f, 0.f};

    for (int k0 = 0; k0 < CC; k0 += 32) {
#pragma unroll
        for (int i = 0; i < 2; i++) {
            const int rbase = wave * 32 + i * 16;
            gload_lds16(A + (size_t)(bm + rbase + srow) * CC + k0 + scol,
                        As + rbase * 32);
            gload_lds16(Bp + (size_t)(bn + rbase + srow) * CC + k0 + scol,
                        Bs + rbase * 32);
        }
        __syncthreads();

        bf16x8 af[4], bf[4];
#pragma unroll
        for (int mi = 0; mi < 4; mi++)
            af[mi] = *(const bf16x8*)(As + (wm * 64 + mi * 16 + l16) * 32 + quad * 8);
#pragma unroll
        for (int ni = 0; ni < 4; ni++)
            bf[ni] = *(const bf16x8*)(Bs + (wn * 64 + ni * 16 + l16) * 32 + quad * 8);
#pragma unroll
        for (int mi = 0; mi < 4; mi++)
#pragma unroll
            for (int ni = 0; ni < 4; ni++)
                acc[mi][ni] = __builtin_amdgcn_mfma_f32_16x16x32_bf16(
                    af[mi], bf[ni], acc[mi][ni], 0, 0, 0);
        __syncthreads();
    }

#pragma unroll
    for (int mi = 0; mi < 4; mi++) {
#pragma unroll
        for (int r = 0; r < 4; r++) {
            const int m = bm + wm * 64 + mi * 16 + quad * 4 + r;
#pragma unroll
            for (int ni = 0; ni < 4; ni++) {
                const int colg = bn + wn * 64 + ni * 16 + l16;
                float v = acc[mi][ni][r];
                if (wsel == 0) v *= 0.18033688f;  // 1/sqrt(64) * log2(e)
                const int t = m >> 1, b = m & 1;
                const int h = colg >> 6, d = colg & 63;
                ushort* dst = (wsel == 0) ? Oq : (wsel == 1) ? Ok : Ov;
                dst[(((size_t)(b * HH + h)) * TT + t) * DD + d] = f2b(v);
            }
        }
    }
}

// ---------------------------------------------------------------------------
// Out-projection GEMM: 128x64 tile (512 blocks = 2/CU), BK=32, fp32 output.
// ---------------------------------------------------------------------------
__global__ __launch_bounds__(256) void gemm_out(const ushort* __restrict__ A,
                                                const ushort* __restrict__ Bm,
                                                float* __restrict__ Of) {
    __shared__ __align__(16) ushort As[128 * 32];   // 8 KB
    __shared__ __align__(16) ushort Bs[64 * 32];    // 4 KB

    const int tid = threadIdx.x;
    const int wave = tid >> 6, lane = tid & 63;
    const int quad = lane >> 4, l16 = lane & 15;

    const int bm = blockIdx.x * 128;
    const int bn = blockIdx.y * 64;

    const int srow = lane >> 2;
    const int scol = (lane & 3) * 8;

    f32x4 acc[2][4];
#pragma unroll
    for (int i = 0; i < 2; i++)
#pragma unroll
        for (int j = 0; j < 4; j++) acc[i][j] = (f32x4){0.f, 0.f, 0.f, 0.f};

    for (int k0 = 0; k0 < CC; k0 += 32) {
#pragma unroll
        for (int i = 0; i < 2; i++) {
            const int rbase = wave * 32 + i * 16;
            gload_lds16(A + (size_t)(bm + rbase + srow) * CC + k0 + scol,
                        As + rbase * 32);
        }
        gload_lds16(Bm + (size_t)(bn + wave * 16 + srow) * CC + k0 + scol,
                    Bs + wave * 16 * 32);
        __syncthreads();

        bf16x8 af[2], bf[4];
#pragma unroll
        for (int mi = 0; mi < 2; mi++)
            af[mi] = *(const bf16x8*)(As + (wave * 32 + mi * 16 + l16) * 32 + quad * 8);
#pragma unroll
        for (int ni = 0; ni < 4; ni++)
            bf[ni] = *(const bf16x8*)(Bs + (ni * 16 + l16) * 32 + quad * 8);
#pragma unroll
        for (int mi = 0; mi < 2; mi++)
#pragma unroll
            for (int ni = 0; ni < 4; ni++)
                acc[mi][ni] = __builtin_amdgcn_mfma_f32_16x16x32_bf16(
                    af[mi], bf[ni], acc[mi][ni], 0, 0, 0);
        __syncthreads();
    }

#pragma unroll
    for (int mi = 0; mi < 2; mi++)
#pragma unroll
        for (int r = 0; r < 4; r++) {
            const int m = bm + wave * 32 + mi * 16 + quad * 4 + r;
#pragma unroll
            for (int ni = 0; ni < 4; ni++)
                Of[(size_t)m * CC + bn + ni * 16 + l16] = acc[mi][ni][r];
        }
}

// ---------------------------------------------------------------------------
// prep_kv: rewrite K and V into MFMA-fragment-major layout per 64-key tile:
//   Kf[bh][tile][c][nb][lane][u] = K[j=nb*16+(lane&15)][k=c*32+(lane>>4)*8+u]
//     (serves as the A-operand of the SWAPPED QK: row = key, k = d)
//   Vf[bh][tile][c][db][lane][u] = V[j=kappa][d=db*16+(lane&15)],
//     kappa(c,quad,u) = 16*((8c+u)>>2) + 4*quad + (u&3)
//     chosen so the PV A-operand packs from each lane's OWN 16 post-softmax
//     values (swapped-QK output) with zero cross-lane traffic.
// ---------------------------------------------------------------------------
__global__ __launch_bounds__(256) void prep_kv(const ushort* __restrict__ Kb,
                                               const ushort* __restrict__ Vb,
                                               ushort* __restrict__ Kf,
                                               ushort* __restrict__ Vf) {
    __shared__ __align__(16) ushort Ls[64 * 72];
    const int tile = blockIdx.x;      // 0..31
    const int bh   = blockIdx.y;
    const int t    = threadIdx.x;
    const size_t src = (size_t)bh * TT * DD + (size_t)tile * 64 * DD;
    const size_t dst = (size_t)bh * TT * DD + (size_t)tile * 4096;

    // ---- K: stage tile (coalesced), emit fragment-major (coalesced) ----
#pragma unroll
    for (int i = 0; i < 2; i++) {
        int e = t + i * 256;
        int r = e >> 3, kc = (e & 7) * 8;
        *(uint4*)(Ls + r * 72 + kc) = *(const uint4*)(Kb + src + r * 64 + kc);
    }
    __syncthreads();
#pragma unroll
    for (int i = 0; i < 2; i++) {
        int o = t + i * 256;          // output 16B chunk id, 0..511
        int c = o >> 8, nb = (o >> 6) & 3, lane = o & 63;
        int quad = lane >> 4, l16 = lane & 15;
        int j = nb * 16 + l16, k0 = c * 32 + quad * 8;
        *(uint4*)(Kf + dst + (size_t)o * 8) = *(const uint4*)(Ls + j * 72 + k0);
    }
    __syncthreads();

    // ---- V: stage tile, emit transposed+permuted fragment-major ----
#pragma unroll
    for (int i = 0; i < 2; i++) {
        int e = t + i * 256;
        int r = e >> 3, kc = (e & 7) * 8;
        *(uint4*)(Ls + r * 72 + kc) = *(const uint4*)(Vb + src + r * 64 + kc);
    }
    __syncthreads();
#pragma unroll
    for (int i = 0; i < 2; i++) {
        int o = t + i * 256;
        int c = o >> 8, db = (o >> 6) & 3, lane = o & 63;
        int quad = lane >> 4, l16 = lane & 15;
        int d = db * 16 + l16;
        ushort tmp[8];
#pragma unroll
        for (int u = 0; u < 8; u++) {
            int j = 16 * ((8 * c + u) >> 2) + 4 * quad + (u & 3);   // kappa
            tmp[u] = Ls[j * 72 + d];
        }
        *(uint4*)(Vf + dst + (size_t)o * 8) = *(uint4*)tmp;
    }
}

// ---------------------------------------------------------------------------
// Flash step with SWAPPED QK^T and fully in-register softmax (no LDS at all).
//   S[nb] = mfma(kf[c*4+nb], qa[c], S[nb])  -> lane (quad,l16) holds
//   P[key=j0+16nb+4quad+r][query=q0+l16]: 16 P-values per lane, one query.
//   exp2 + l-sum in-lane; PV A-operand packed from the lane's own values
//   (V permutation kappa matches), 8 cvt_pk, zero cross-lane, zero LDS.
// This deletes the P LDS round-trip (write+lgkm+read+bank conflicts) that
// was the serial chain invariant across R0/R4/R5.
// ---------------------------------------------------------------------------
template <bool DIAG>
__device__ __forceinline__ void attn_step(const bf16x8* qa, f32x4* O, float& l,
                                          const bf16x8* kf, const bf16x8* vf,
                                          int j0, int qg, int quad) {
    f32x4 S[4];
#pragma unroll
    for (int nb = 0; nb < 4; nb++) S[nb] = (f32x4){0.f, 0.f, 0.f, 0.f};
#pragma unroll
    for (int c = 0; c < 2; c++)
#pragma unroll
        for (int nb = 0; nb < 4; nb++)
            S[nb] = __builtin_amdgcn_mfma_f32_16x16x32_bf16(kf[c * 4 + nb],
                                                            qa[c], S[nb], 0, 0, 0);

    float p[4][4];   // [nb][r], key = j0 + nb*16 + quad*4 + r
#pragma unroll
    for (int nb = 0; nb < 4; nb++)
#pragma unroll
        for (int r = 0; r < 4; r++) {
            float s = S[nb][r];
            if (DIAG) { if (j0 + nb * 16 + quad * 4 + r > qg) s = -1e30f; }
            p[nb][r] = __builtin_amdgcn_exp2f(s);
        }
#pragma unroll
    for (int nb = 0; nb < 4; nb++)
        l += (p[nb][0] + p[nb][1]) + (p[nb][2] + p[nb][3]);

    // PV A-operand: dword w of pa[c] covers kslots u=2w,2w+1 ->
    // nb = 2c + (w>>1), r = (w&1)*2 + {0,1}  (matches kappa in prep_kv)
    union { unsigned w[4]; bf16x8 v; } pa0, pa1;
#pragma unroll
    for (int w = 0; w < 4; w++) {
        const int nb = w >> 1;
        const int rb = (w & 1) * 2;
        pa0.w[w] = pack_bf16(p[nb][rb], p[nb][rb + 1]);
        pa1.w[w] = pack_bf16(p[2 + nb][rb], p[2 + nb][rb + 1]);
    }
#pragma unroll
    for (int db = 0; db < 4; db++)
        O[db] = __builtin_amdgcn_mfma_f32_16x16x32_bf16(pa0.v, vf[db], O[db], 0, 0, 0);
#pragma unroll
    for (int db = 0; db < 4; db++)
        O[db] = __builtin_amdgcn_mfma_f32_16x16x32_bf16(pa1.v, vf[4 + db], O[db], 0, 0, 0);
}

// ---------------------------------------------------------------------------
// Paired-tile flash MFMA attention, in-register softmax version.
// Block p handles q-tiles p and 31-p (uniform 33 tile-visits). K/V from
// fragment-major global buffers via fully-coalesced 1KB loads. ZERO LDS,
// zero barriers, zero bank conflicts in the whole kernel; per-lane scalar
// l accumulators reduced once in the epilogue (2 xor-shuffles + 4 shfl).
// XCD decode kept: xcd owns bh in [4*xcd,4*xcd+4) (2MB K/V per L2).
// O layout is unchanged (query=4quad+r, d=db*16+l16): same epilogue stores.
// ---------------------------------------------------------------------------
__global__ __launch_bounds__(256, 2) void attn_mfma(const ushort* __restrict__ Qb,
                                                    const ushort* __restrict__ Kf,
                                                    const ushort* __restrict__ Vf,
                                                    ushort* __restrict__ ctx) {
    const int tid  = threadIdx.x;
    const int wave = tid >> 6;
    const int lane = tid & 63;
    const int quad = lane >> 4;
    const int l16  = lane & 15;

    // XCD-locality decode: xcd = bidx&7 owns bh in [4*xcd, 4*xcd+4)
    const int bidx = blockIdx.x;                  // 0..511
    const int xcd  = bidx & 7;
    const int slot = bidx >> 3;                   // 0..63
    const int bh   = xcd * 4 + (slot >> 4);       // 0..31
    const int p    = slot & 15;                   // 0..15

    const int qtA = p, qtB = (TT / 64 - 1) - p;   // qtA < 16 <= qtB
    const int q0A = qtA * 64 + wave * 16;
    const int q0B = qtB * 64 + wave * 16;
    const int qgA = q0A + l16;                    // this lane's A query
    const int qgB = q0B + l16;                    // this lane's B query

    const size_t baseQK = (size_t)bh * TT * DD;

    bf16x8 qaA[2], qaB[2];
    {
        const ushort* qp = Qb + baseQK + (size_t)(q0A + l16) * DD + quad * 8;
        qaA[0] = *(const bf16x8*)(qp);
        qaA[1] = *(const bf16x8*)(qp + 32);
        const ushort* qp2 = Qb + baseQK + (size_t)(q0B + l16) * DD + quad * 8;
        qaB[0] = *(const bf16x8*)(qp2);
        qaB[1] = *(const bf16x8*)(qp2 + 32);
    }

    f32x4 OA[4], OB[4];
#pragma unroll
    for (int i = 0; i < 4; i++) {
        OA[i] = (f32x4){0.f, 0.f, 0.f, 0.f};
        OB[i] = (f32x4){0.f, 0.f, 0.f, 0.f};
    }
    float lA = 0.f, lB = 0.f;   // per-lane partial denom (query = q0+l16)

    const ushort* Kfp = Kf + baseQK;   // +4096 per tile
    const ushort* Vfp = Vf + baseQK;

    for (int kt = 0; kt <= qtB; kt++) {
        const int j0 = kt * 64;

        // coalesced fragment loads: chunk i is 1KB contiguous, lane*16B apart
        bf16x8 kf[8], vf[8];
#pragma unroll
        for (int i = 0; i < 8; i++) {
            kf[i] = *(const bf16x8*)(Kfp + (i << 9) + lane * 8);
            vf[i] = *(const bf16x8*)(Vfp + (i << 9) + lane * 8);
        }

        if (kt == qtB)
            attn_step<true >(qaB, OB, lB, kf, vf, j0, qgB, quad);
        else
            attn_step<false>(qaB, OB, lB, kf, vf, j0, qgB, quad);

        if (kt < qtA)
            attn_step<false>(qaA, OA, lA, kf, vf, j0, qgA, quad);
        else if (kt == qtA)
            attn_step<true >(qaA, OA, lA, kf, vf, j0, qgA, quad);

        Kfp += 4096;
        Vfp += 4096;
    }

    // epilogue: complete l across the 4 quads holding this query's keys,
    // then fetch the denom for the queries THIS lane's O rows belong to.
    lA += __shfl_xor(lA, 16); lA += __shfl_xor(lA, 32);
    lB += __shfl_xor(lB, 16); lB += __shfl_xor(lB, 32);

    const int b = bh >> 4, h = bh & 15;
#pragma unroll
    for (int r = 0; r < 4; r++) {
        const float invA = 1.f / __shfl(lA, quad * 4 + r);
        const float invB = 1.f / __shfl(lB, quad * 4 + r);
        const int tA = q0A + quad * 4 + r;
        const int tB = q0B + quad * 4 + r;
#pragma unroll
        for (int db = 0; db < 4; db++) {
            ctx[((size_t)tA * BB + b) * CC + h * DD + db * 16 + l16] =
                f2b(OA[db][r] * invA);
            ctx[((size_t)tB * BB + b) * CC + h * DD + db * 16 + l16] =
                f2b(OB[db][r] * invB);
        }
    }
}

// ---------------------------------------------------------------------------
extern "C" void kernel_launch(void* const* d_in, const int* in_sizes, int n_in,
                              void* d_out, int out_size, void* d_ws, size_t ws_size,
                              hipStream_t stream) {
    const float* x  = (const float*)d_in[0];
    const float* Wq = (const float*)d_in[1];
    const float* Wk = (const float*)d_in[2];
    const float* Wv = (const float*)d_in[3];
    const float* Wo = (const float*)d_in[4];
    float* out = (float*)d_out;

    // Workspace (bf16): xb 8MB | Wb 8MB | Qb 8 | Kb 8 | Vb 8 | Kf 8 | Vf 8 | Ctxb 8 = 64MB
    ushort* xb  = (ushort*)d_ws;
    ushort* Wb  = xb + (size_t)MM * CC;
    ushort* Wqb = Wb;
    ushort* Wkb = Wb + (size_t)CC * CC;
    ushort* Wvb = Wb + 2 * (size_t)CC * CC;
    ushort* Wob = Wb + 3 * (size_t)CC * CC;
    ushort* Qb  = Wb + 4 * (size_t)CC * CC;
    ushort* Kb  = Qb + (size_t)MM * CC;
    ushort* Vb  = Kb + (size_t)MM * CC;
    ushort* Kf  = Vb + (size_t)MM * CC;
    ushort* Vf  = Kf + (size_t)MM * CC;
    ushort* Ctxb = Vf + (size_t)MM * CC;

    conv_all<<<dim3((XQUADS + 4 * WQUADS) / 256), 256, 0, stream>>>(
        x, Wq, Wk, Wv, Wo, xb);

    gemm_qkv<<<dim3(MM / 128, 24), 256, 0, stream>>>(
        xb, Wqb, Wkb, Wvb, Qb, Kb, Vb);

    prep_kv<<<dim3(TT / 64, BB * HH), 256, 0, stream>>>(Kb, Vb, Kf, Vf);

    attn_mfma<<<dim3(512), 256, 0, stream>>>(Qb, Kf, Vf, Ctxb);

    gemm_out<<<dim3(MM / 128, CC / 64), 256, 0, stream>>>(Ctxb, Wob, out);
}

// Round 7
// 169.708 us; speedup vs baseline: 1.0514x; 1.0514x over previous
//
#include <hip/hip_runtime.h>
#include <hip/hip_bf16.h>

// Problem constants (reference: T=2048, B=2, D_MODEL=1024, H=16, HEAD_DIM=64)
#define TT 2048
#define BB 2
#define CC 1024
#define HH 16
#define DD 64
#define MM (TT * BB)   // 4096 rows in the projection GEMMs

typedef short bf16x8 __attribute__((ext_vector_type(8)));   // 8 bf16 in 4 VGPRs
typedef float f32x4  __attribute__((ext_vector_type(4)));

// float -> bf16 (round-nearest-even), bit-level
__device__ inline ushort f2b(float f) {
    union { float f; unsigned u; } v; v.f = f;
    unsigned r = v.u + 0x7FFFu + ((v.u >> 16) & 1u);
    return (ushort)(r >> 16);
}

// pack 2 floats -> 2 bf16 in one dword
__device__ inline unsigned pack_bf16(float a, float b) {
    __hip_bfloat162 h = __float22bfloat162_rn(make_float2(a, b));
    union { __hip_bfloat162 h; unsigned u; } c; c.h = h;
    return c.u;
}

// async global->LDS, 16B per lane
__device__ inline void gload_lds16(const ushort* g, ushort* l) {
    __builtin_amdgcn_global_load_lds(
        (const __attribute__((address_space(1))) void*)g,
        (__attribute__((address_space(3))) void*)l, 16, 0, 0);
}

// ---------------------------------------------------------------------------
// fp32 -> bf16 convert, x and all four W in one launch.
// ---------------------------------------------------------------------------
#define XQUADS (MM * CC / 4)          // 1048576
#define WQUADS (CC * CC / 4)          // 262144
__global__ __launch_bounds__(256) void conv_all(const float* __restrict__ x,
                                                const float* __restrict__ Wq,
                                                const float* __restrict__ Wk,
                                                const float* __restrict__ Wv,
                                                const float* __restrict__ Wo,
                                                ushort* __restrict__ dst) {
    int idx = blockIdx.x * 256 + threadIdx.x;    // quad index
    const float* src;
    int off;
    if (idx < XQUADS) {
        src = x; off = idx;
    } else {
        int wi = (idx - XQUADS) >> 18;           // WQUADS == 2^18
        off = (idx - XQUADS) & (WQUADS - 1);
        src = (wi == 0) ? Wq : (wi == 1) ? Wk : (wi == 2) ? Wv : Wo;
    }
    float4 v = ((const float4*)src)[off];
    ushort4 o = {f2b(v.x), f2b(v.y), f2b(v.z), f2b(v.w)};
    ((ushort4*)dst)[idx] = o;
}

// ---------------------------------------------------------------------------
// bf16 MFMA NT GEMM (m97 structure), 128x128 tile, BK=32, 4 waves (2x2).
// Fused QKV (grid.y = 24): wsel = by>>3 picks B/out; epilogue scatters bf16
// to (B,H,T,D); Q scaled by 1/sqrt(64)*log2(e) so attention uses exp2 raw.
// ---------------------------------------------------------------------------
__global__ __launch_bounds__(256) void gemm_qkv(const ushort* __restrict__ A,
                                                const ushort* __restrict__ B0,
                                                const ushort* __restrict__ B1,
                                                const ushort* __restrict__ B2,
                                                ushort* __restrict__ Oq,
                                                ushort* __restrict__ Ok,
                                                ushort* __restrict__ Ov) {
    __shared__ __align__(16) ushort As[128 * 32];
    __shared__ __align__(16) ushort Bs[128 * 32];

    const int tid = threadIdx.x;
    const int wave = tid >> 6, lane = tid & 63;
    const int quad = lane >> 4, l16 = lane & 15;
    const int wm = wave >> 1, wn = wave & 1;

    const int bm = blockIdx.x * 128;
    const int by = blockIdx.y;
    const int wsel = by >> 3;
    const ushort* Bp = (wsel == 0) ? B0 : (wsel == 1) ? B1 : B2;
    const int bn = (by & 7) * 128;

    const int srow = lane >> 2;
    const int scol = (lane & 3) * 8;

    f32x4 acc[4][4];
#pragma unroll
    for (int i = 0; i < 4; i++)
#pragma unroll
        for (int j = 0; j < 4; j++) acc[i][j] = (f32x4){0.f, 0.f, 0.f, 0.f};

    for (int k0 = 0; k0 < CC; k0 += 32) {
#pragma unroll
        for (int i = 0; i < 2; i++) {
            const int rbase = wave * 32 + i * 16;
            gload_lds16(A + (size_t)(bm + rbase + srow) * CC + k0 + scol,
                        As + rbase * 32);
            gload_lds16(Bp + (size_t)(bn + rbase + srow) * CC + k0 + scol,
                        Bs + rbase * 32);
        }
        __syncthreads();

        bf16x8 af[4], bf[4];
#pragma unroll
        for (int mi = 0; mi < 4; mi++)
            af[mi] = *(const bf16x8*)(As + (wm * 64 + mi * 16 + l16) * 32 + quad * 8);
#pragma unroll
        for (int ni = 0; ni < 4; ni++)
            bf[ni] = *(const bf16x8*)(Bs + (wn * 64 + ni * 16 + l16) * 32 + quad * 8);
#pragma unroll
        for (int mi = 0; mi < 4; mi++)
#pragma unroll
            for (int ni = 0; ni < 4; ni++)
                acc[mi][ni] = __builtin_amdgcn_mfma_f32_16x16x32_bf16(
                    af[mi], bf[ni], acc[mi][ni], 0, 0, 0);
        __syncthreads();
    }

#pragma unroll
    for (int mi = 0; mi < 4; mi++) {
#pragma unroll
        for (int r = 0; r < 4; r++) {
            const int m = bm + wm * 64 + mi * 16 + quad * 4 + r;
#pragma unroll
            for (int ni = 0; ni < 4; ni++) {
                const int colg = bn + wn * 64 + ni * 16 + l16;
                float v = acc[mi][ni][r];
                if (wsel == 0) v *= 0.18033688f;  // 1/sqrt(64) * log2(e)
                const int t = m >> 1, b = m & 1;
                const int h = colg >> 6, d = colg & 63;
                ushort* dst = (wsel == 0) ? Oq : (wsel == 1) ? Ok : Ov;
                dst[(((size_t)(b * HH + h)) * TT + t) * DD + d] = f2b(v);
            }
        }
    }
}

// ---------------------------------------------------------------------------
// Out-projection GEMM: 128x64 tile (512 blocks = 2/CU), BK=32, fp32 output.
// ---------------------------------------------------------------------------
__global__ __launch_bounds__(256) void gemm_out(const ushort* __restrict__ A,
                                                const ushort* __restrict__ Bm,
                                                float* __restrict__ Of) {
    __shared__ __align__(16) ushort As[128 * 32];   // 8 KB
    __shared__ __align__(16) ushort Bs[64 * 32];    // 4 KB

    const int tid = threadIdx.x;
    const int wave = tid >> 6, lane = tid & 63;
    const int quad = lane >> 4, l16 = lane & 15;

    const int bm = blockIdx.x * 128;
    const int bn = blockIdx.y * 64;

    const int srow = lane >> 2;
    const int scol = (lane & 3) * 8;

    f32x4 acc[2][4];
#pragma unroll
    for (int i = 0; i < 2; i++)
#pragma unroll
        for (int j = 0; j < 4; j++) acc[i][j] = (f32x4){0.f, 0.f, 0.f, 0.f};

    for (int k0 = 0; k0 < CC; k0 += 32) {
#pragma unroll
        for (int i = 0; i < 2; i++) {
            const int rbase = wave * 32 + i * 16;
            gload_lds16(A + (size_t)(bm + rbase + srow) * CC + k0 + scol,
                        As + rbase * 32);
        }
        gload_lds16(Bm + (size_t)(bn + wave * 16 + srow) * CC + k0 + scol,
                    Bs + wave * 16 * 32);
        __syncthreads();

        bf16x8 af[2], bf[4];
#pragma unroll
        for (int mi = 0; mi < 2; mi++)
            af[mi] = *(const bf16x8*)(As + (wave * 32 + mi * 16 + l16) * 32 + quad * 8);
#pragma unroll
        for (int ni = 0; ni < 4; ni++)
            bf[ni] = *(const bf16x8*)(Bs + (ni * 16 + l16) * 32 + quad * 8);
#pragma unroll
        for (int mi = 0; mi < 2; mi++)
#pragma unroll
            for (int ni = 0; ni < 4; ni++)
                acc[mi][ni] = __builtin_amdgcn_mfma_f32_16x16x32_bf16(
                    af[mi], bf[ni], acc[mi][ni], 0, 0, 0);
        __syncthreads();
    }

#pragma unroll
    for (int mi = 0; mi < 2; mi++)
#pragma unroll
        for (int r = 0; r < 4; r++) {
            const int m = bm + wave * 32 + mi * 16 + quad * 4 + r;
#pragma unroll
            for (int ni = 0; ni < 4; ni++)
                Of[(size_t)m * CC + bn + ni * 16 + l16] = acc[mi][ni][r];
        }
}

// ---------------------------------------------------------------------------
// prep_kv: rewrite K and V into MFMA-fragment-major layout per 64-key tile:
//   Kf[bh][tile][c][nb][lane][u] = K[j=nb*16+(lane&15)][k=c*32+(lane>>4)*8+u]
//     (serves as the A-operand of the SWAPPED QK: row = key, k = d)
//   Vf[bh][tile][c][db][lane][u] = V[j=kappa][d=db*16+(lane&15)],
//     kappa(c,quad,u) = 16*((8c+u)>>2) + 4*quad + (u&3)
//     chosen so the PV A-operand packs from each lane's OWN 16 post-softmax
//     values (swapped-QK output) with zero cross-lane traffic.
// ---------------------------------------------------------------------------
__global__ __launch_bounds__(256) void prep_kv(const ushort* __restrict__ Kb,
                                               const ushort* __restrict__ Vb,
                                               ushort* __restrict__ Kf,
                                               ushort* __restrict__ Vf) {
    __shared__ __align__(16) ushort Ls[64 * 72];
    const int tile = blockIdx.x;      // 0..31
    const int bh   = blockIdx.y;
    const int t    = threadIdx.x;
    const size_t src = (size_t)bh * TT * DD + (size_t)tile * 64 * DD;
    const size_t dst = (size_t)bh * TT * DD + (size_t)tile * 4096;

    // ---- K: stage tile (coalesced), emit fragment-major (coalesced) ----
#pragma unroll
    for (int i = 0; i < 2; i++) {
        int e = t + i * 256;
        int r = e >> 3, kc = (e & 7) * 8;
        *(uint4*)(Ls + r * 72 + kc) = *(const uint4*)(Kb + src + r * 64 + kc);
    }
    __syncthreads();
#pragma unroll
    for (int i = 0; i < 2; i++) {
        int o = t + i * 256;          // output 16B chunk id, 0..511
        int c = o >> 8, nb = (o >> 6) & 3, lane = o & 63;
        int quad = lane >> 4, l16 = lane & 15;
        int j = nb * 16 + l16, k0 = c * 32 + quad * 8;
        *(uint4*)(Kf + dst + (size_t)o * 8) = *(const uint4*)(Ls + j * 72 + k0);
    }
    __syncthreads();

    // ---- V: stage tile, emit transposed+permuted fragment-major ----
#pragma unroll
    for (int i = 0; i < 2; i++) {
        int e = t + i * 256;
        int r = e >> 3, kc = (e & 7) * 8;
        *(uint4*)(Ls + r * 72 + kc) = *(const uint4*)(Vb + src + r * 64 + kc);
    }
    __syncthreads();
#pragma unroll
    for (int i = 0; i < 2; i++) {
        int o = t + i * 256;
        int c = o >> 8, db = (o >> 6) & 3, lane = o & 63;
        int quad = lane >> 4, l16 = lane & 15;
        int d = db * 16 + l16;
        ushort tmp[8];
#pragma unroll
        for (int u = 0; u < 8; u++) {
            int j = 16 * ((8 * c + u) >> 2) + 4 * quad + (u & 3);   // kappa
            tmp[u] = Ls[j * 72 + d];
        }
        *(uint4*)(Vf + dst + (size_t)o * 8) = *(uint4*)tmp;
    }
}

// ---------------------------------------------------------------------------
// Flash step with SWAPPED QK^T and fully in-register softmax.
//   S[nb] = mfma(kf[c*4+nb], qa[c], S[nb])  -> lane (quad,l16) holds
//   P[key=j0+16nb+4quad+r][query=q0+l16]: 16 P-values per lane, one query.
//   exp2 + l-sum in-lane; PV A-operand packed from the lane's own values
//   (V permutation kappa matches), 8 cvt_pk, zero cross-lane.
// ---------------------------------------------------------------------------
template <bool DIAG>
__device__ __forceinline__ void attn_step(const bf16x8* qa, f32x4* O, float& l,
                                          const bf16x8* kf, const bf16x8* vf,
                                          int j0, int qg, int quad) {
    f32x4 S[4];
#pragma unroll
    for (int nb = 0; nb < 4; nb++) S[nb] = (f32x4){0.f, 0.f, 0.f, 0.f};
#pragma unroll
    for (int c = 0; c < 2; c++)
#pragma unroll
        for (int nb = 0; nb < 4; nb++)
            S[nb] = __builtin_amdgcn_mfma_f32_16x16x32_bf16(kf[c * 4 + nb],
                                                            qa[c], S[nb], 0, 0, 0);

    float p[4][4];   // [nb][r], key = j0 + nb*16 + quad*4 + r
#pragma unroll
    for (int nb = 0; nb < 4; nb++)
#pragma unroll
        for (int r = 0; r < 4; r++) {
            float s = S[nb][r];
            if (DIAG) { if (j0 + nb * 16 + quad * 4 + r > qg) s = -1e30f; }
            p[nb][r] = __builtin_amdgcn_exp2f(s);
        }
#pragma unroll
    for (int nb = 0; nb < 4; nb++)
        l += (p[nb][0] + p[nb][1]) + (p[nb][2] + p[nb][3]);

    // PV A-operand: dword w of pa[c] covers kslots u=2w,2w+1 ->
    // nb = 2c + (w>>1), r = (w&1)*2 + {0,1}  (matches kappa in prep_kv)
    union { unsigned w[4]; bf16x8 v; } pa0, pa1;
#pragma unroll
    for (int w = 0; w < 4; w++) {
        const int nb = w >> 1;
        const int rb = (w & 1) * 2;
        pa0.w[w] = pack_bf16(p[nb][rb], p[nb][rb + 1]);
        pa1.w[w] = pack_bf16(p[2 + nb][rb], p[2 + nb][rb + 1]);
    }
#pragma unroll
    for (int db = 0; db < 4; db++)
        O[db] = __builtin_amdgcn_mfma_f32_16x16x32_bf16(pa0.v, vf[db], O[db], 0, 0, 0);
#pragma unroll
    for (int db = 0; db < 4; db++)
        O[db] = __builtin_amdgcn_mfma_f32_16x16x32_bf16(pa1.v, vf[4 + db], O[db], 0, 0, 0);
}

// ---------------------------------------------------------------------------
// Paired-tile flash MFMA attention: in-register softmax (R6) + LDS-staged
// K/V double-buffer (R4 mechanism) — the combination.
//
// R6 post-mortem (issue accounting that finally adds up): per step-pair
// window ~3054cy = L1 ~2048cy (8 waves/CU x 16KB each re-read through one
// 64B/cy L1) + VALU ~977cy + MFMA ~458cy overlapped. L1 is the binder.
// Fix: stage each 16KB K/V tile ONCE per block via global_load_lds double
// buffer (L1 sees 32KB/CU/window ~ 512cy), waves read via conflict-free
// contiguous ds_read_b128 (128B/cy pipe). P stays in registers, so LDS
// carries ONLY K/V — R4's P-conflict/lgkm overhead is gone. DMA issued at
// the top of each step has the full ~1500cy compute to land before the
// barrier drain (T3-minimum pipeline).
// LDS: 2 x 16KB = 32KB/block, 2 blocks/CU. XCD decode kept.
// ---------------------------------------------------------------------------
__global__ __launch_bounds__(256, 2) void attn_mfma(const ushort* __restrict__ Qb,
                                                    const ushort* __restrict__ Kf,
                                                    const ushort* __restrict__ Vf,
                                                    ushort* __restrict__ ctx) {
    __shared__ __align__(16) ushort KV[2][8192];  // [buf][chunks 0-7 K, 8-15 V]

    const int tid  = threadIdx.x;
    const int wave = tid >> 6;
    const int lane = tid & 63;
    const int quad = lane >> 4;
    const int l16  = lane & 15;

    // XCD-locality decode: xcd = bidx&7 owns bh in [4*xcd, 4*xcd+4)
    const int bidx = blockIdx.x;                  // 0..511
    const int xcd  = bidx & 7;
    const int slot = bidx >> 3;                   // 0..63
    const int bh   = xcd * 4 + (slot >> 4);       // 0..31
    const int p    = slot & 15;                   // 0..15

    const int qtA = p, qtB = (TT / 64 - 1) - p;   // qtA < 16 <= qtB
    const int q0A = qtA * 64 + wave * 16;
    const int q0B = qtB * 64 + wave * 16;
    const int qgA = q0A + l16;                    // this lane's A query
    const int qgB = q0B + l16;                    // this lane's B query

    const size_t baseQK = (size_t)bh * TT * DD;

    bf16x8 qaA[2], qaB[2];
    {
        const ushort* qp = Qb + baseQK + (size_t)(q0A + l16) * DD + quad * 8;
        qaA[0] = *(const bf16x8*)(qp);
        qaA[1] = *(const bf16x8*)(qp + 32);
        const ushort* qp2 = Qb + baseQK + (size_t)(q0B + l16) * DD + quad * 8;
        qaB[0] = *(const bf16x8*)(qp2);
        qaB[1] = *(const bf16x8*)(qp2 + 32);
    }

    f32x4 OA[4], OB[4];
#pragma unroll
    for (int i = 0; i < 4; i++) {
        OA[i] = (f32x4){0.f, 0.f, 0.f, 0.f};
        OB[i] = (f32x4){0.f, 0.f, 0.f, 0.f};
    }
    float lA = 0.f, lB = 0.f;   // per-lane partial denom (query = q0+l16)

    const ushort* Kfp = Kf + baseQK;   // +4096 per tile
    const ushort* Vfp = Vf + baseQK;

    // stage one 16KB K/V tile into KV[buf]: wave w DMAs K chunks {2w,2w+1}
    // and V chunks {2w,2w+1} (wave-uniform LDS base + lane*16B, linear).
    auto stage = [&](int buf, const ushort* kp, const ushort* vp) {
#pragma unroll
        for (int i = 0; i < 2; i++) {
            const int ch = wave * 2 + i;           // 0..7 across 4 waves
            gload_lds16(kp + (ch << 9) + lane * 8, &KV[buf][ch << 9]);
            gload_lds16(vp + (ch << 9) + lane * 8, &KV[buf][(8 + ch) << 9]);
        }
    };

    stage(0, Kfp, Vfp);
    __syncthreads();

    int cur = 0;
    for (int kt = 0; kt <= qtB; kt++) {
        // issue next tile's DMA before touching this tile's data
        if (kt < qtB) stage(cur ^ 1, Kfp + 4096, Vfp + 4096);

        // fragment loads from LDS: contiguous 1KB per chunk, lane*16B apart
        bf16x8 kf[8], vf[8];
#pragma unroll
        for (int i = 0; i < 8; i++) {
            kf[i] = *(const bf16x8*)(&KV[cur][i << 9] + lane * 8);
            vf[i] = *(const bf16x8*)(&KV[cur][(8 + i) << 9] + lane * 8);
        }

        const int j0 = kt * 64;
        if (kt == qtB)
            attn_step<true >(qaB, OB, lB, kf, vf, j0, qgB, quad);
        else
            attn_step<false>(qaB, OB, lB, kf, vf, j0, qgB, quad);

        if (kt < qtA)
            attn_step<false>(qaA, OA, lA, kf, vf, j0, qgA, quad);
        else if (kt == qtA)
            attn_step<true >(qaA, OA, lA, kf, vf, j0, qgA, quad);

        __syncthreads();   // publishes buf cur^1; protects cur for overwrite
        cur ^= 1;
        Kfp += 4096;
        Vfp += 4096;
    }

    // epilogue: complete l across the 4 quads holding this query's keys,
    // then fetch the denom for the queries THIS lane's O rows belong to.
    lA += __shfl_xor(lA, 16); lA += __shfl_xor(lA, 32);
    lB += __shfl_xor(lB, 16); lB += __shfl_xor(lB, 32);

    const int b = bh >> 4, h = bh & 15;
#pragma unroll
    for (int r = 0; r < 4; r++) {
        const float invA = 1.f / __shfl(lA, quad * 4 + r);
        const float invB = 1.f / __shfl(lB, quad * 4 + r);
        const int tA = q0A + quad * 4 + r;
        const int tB = q0B + quad * 4 + r;
#pragma unroll
        for (int db = 0; db < 4; db++) {
            ctx[((size_t)tA * BB + b) * CC + h * DD + db * 16 + l16] =
                f2b(OA[db][r] * invA);
            ctx[((size_t)tB * BB + b) * CC + h * DD + db * 16 + l16] =
                f2b(OB[db][r] * invB);
        }
    }
}

// ---------------------------------------------------------------------------
extern "C" void kernel_launch(void* const* d_in, const int* in_sizes, int n_in,
                              void* d_out, int out_size, void* d_ws, size_t ws_size,
                              hipStream_t stream) {
    const float* x  = (const float*)d_in[0];
    const float* Wq = (const float*)d_in[1];
    const float* Wk = (const float*)d_in[2];
    const float* Wv = (const float*)d_in[3];
    const float* Wo = (const float*)d_in[4];
    float* out = (float*)d_out;

    // Workspace (bf16): xb 8MB | Wb 8MB | Qb 8 | Kb 8 | Vb 8 | Kf 8 | Vf 8 | Ctxb 8 = 64MB
    ushort* xb  = (ushort*)d_ws;
    ushort* Wb  = xb + (size_t)MM * CC;
    ushort* Wqb = Wb;
    ushort* Wkb = Wb + (size_t)CC * CC;
    ushort* Wvb = Wb + 2 * (size_t)CC * CC;
    ushort* Wob = Wb + 3 * (size_t)CC * CC;
    ushort* Qb  = Wb + 4 * (size_t)CC * CC;
    ushort* Kb  = Qb + (size_t)MM * CC;
    ushort* Vb  = Kb + (size_t)MM * CC;
    ushort* Kf  = Vb + (size_t)MM * CC;
    ushort* Vf  = Kf + (size_t)MM * CC;
    ushort* Ctxb = Vf + (size_t)MM * CC;

    conv_all<<<dim3((XQUADS + 4 * WQUADS) / 256), 256, 0, stream>>>(
        x, Wq, Wk, Wv, Wo, xb);

    gemm_qkv<<<dim3(MM / 128, 24), 256, 0, stream>>>(
        xb, Wqb, Wkb, Wvb, Qb, Kb, Vb);

    prep_kv<<<dim3(TT / 64, BB * HH), 256, 0, stream>>>(Kb, Vb, Kf, Vf);

    attn_mfma<<<dim3(512), 256, 0, stream>>>(Qb, Kf, Vf, Ctxb);

    gemm_out<<<dim3(MM / 128, CC / 64), 256, 0, stream>>>(Ctxb, Wob, out);
}